// Round 4
// baseline (1686.805 us; speedup 1.0000x reference)
//
#include <hip/hip_runtime.h>

namespace {

constexpr int T = 465;        // (N-1)(N-2)/2 triplets per center
constexpr int M = 31;         // "others" count
constexpr float FCUT = 3.5f;
constexpr float PI_OVER_CUT = 0.8975979010256552f; // pi/3.5
constexpr int REC = 12;       // floats per compacted row record
constexpr int K2_BLOCKS = 512;
constexpr int MAXROWS_HARD = 1024 * 480;

__device__ __forceinline__ float ftanh(float x) {
    x = fminf(fmaxf(x, -15.0f), 15.0f);
    const float e = __expf(2.0f * x);
    return (e - 1.0f) * __builtin_amdgcn_rcpf(e + 1.0f);
}

// ---------------- K1: compact active triplets into global row list ----------
__global__ __launch_bounds__(64, 1)
void feat_kernel(const float* __restrict__ D, const float* __restrict__ Z,
                 float* __restrict__ rows, int* __restrict__ ctr, int maxrows)
{
    const int lane = threadIdx.x;
    const int center = blockIdx.x;
    const int bi = center >> 5, i = center & 31;
    const float* __restrict__ Drow = D + bi * 1024;
    const float* __restrict__ Zrow = Z + bi * 32;
    const float z_i = Zrow[i];

    unsigned long long masks[8];
    int cnt = 0;
    #pragma unroll
    for (int rnd = 0; rnd < 8; ++rnd) {
        const int t = rnd * 64 + lane;
        bool act = false;
        if (t < T) {
            int a = 0, rem = t;
            while (rem >= M - 1 - a) { rem -= M - 1 - a; ++a; }
            const int b = a + 1 + rem;
            const int j = a + (a >= i);
            const int k = b + (b >= i);
            const float rij = Drow[i * 32 + j];
            const float rik = Drow[i * 32 + k];
            act = (rij < FCUT) && (rik < FCUT);
        }
        masks[rnd] = __ballot(act);
        cnt += (int)__popcll(masks[rnd]);
    }
    const int padded = (cnt + 15) & ~15;
    if (padded == 0) return;
    int base = 0;
    if (lane == 0) base = atomicAdd(ctr, padded);
    base = __shfl(base, 0);
    if (base + padded > maxrows) return;

    int pre = 0;
    #pragma unroll
    for (int rnd = 0; rnd < 8; ++rnd) {
        const unsigned long long mb = masks[rnd];
        const bool act = (mb >> lane) & 1ull;
        const int slot = base + pre + (int)__popcll(mb & ((1ull << lane) - 1ull));
        pre += (int)__popcll(mb);
        if (act) {
            const int t = rnd * 64 + lane;
            int a = 0, rem = t;
            while (rem >= M - 1 - a) { rem -= M - 1 - a; ++a; }
            const int b = a + 1 + rem;
            const int j = a + (a >= i);
            const int k = b + (b >= i);
            const float rij = Drow[i * 32 + j];
            const float rik = Drow[i * 32 + k];
            const float rjk = Drow[j * 32 + k];
            const float zj = Zrow[j], zk = Zrow[k];
            const float rij2 = rij * rij, rik2 = rik * rik, rjk2 = rjk * rjk;
            const float ci = (rij2 + rik2 - rjk2) / fmaxf(2.f * rij * rik, 1e-10f);
            const float cj = (rij2 + rjk2 - rik2) / fmaxf(2.f * rij * rjk, 1e-10f);
            const float ck = (rik2 + rjk2 - rij2) / fmaxf(2.f * rik * rjk, 1e-10f);
            const float g0 = rij + rik + rjk;
            const float g1 = rij * rik + rij * rjk + rik * rjk;
            const float g2 = rij * rik * rjk;
            const float rg = 1.0f / (sqrtf(g0 * g0 + g1 * g1 + g2 * g2) + 1e-7f);
            const float s0 = z_i + zj + zk;
            const float s1 = ci + cj + ck;
            const float s2 = z_i * (zj + zk) + zj * zk - ci * (cj + ck) - cj * ck;
            const float s3 = z_i * (cj + ck) + ci * (zj + zk) + zj * ck + cj * zk;
            const float s4 = z_i * (zj * zk - cj * ck) - ci * (zj * ck + cj * zk);
            const float s5 = z_i * (zj * ck + cj * zk) + ci * (zj * zk - cj * ck);
            const float rs = 1.0f / (sqrtf(s0*s0 + s1*s1 + s2*s2 + s3*s3 + s4*s4 + s5*s5) + 1e-7f);
            const float fij = 0.5f * cosf(PI_OVER_CUT * rij) + 0.5f;
            const float fik = 0.5f * cosf(PI_OVER_CUT * rik) + 0.5f;
            float4* dst = (float4*)(rows + (size_t)slot * REC);
            dst[0] = make_float4(g0 * rg, g1 * rg, g2 * rg, s0 * rs);
            dst[1] = make_float4(s1 * rs, s2 * rs, s3 * rs, s4 * rs);
            dst[2] = make_float4(s5 * rs, fij * fik, __int_as_float(center), 0.f);
        }
    }
    for (int p = cnt + lane; p < padded; p += 64) {
        float4* dst = (float4*)(rows + (size_t)(base + p) * REC);
        dst[0] = make_float4(0.f, 0.f, 0.f, 0.f);
        dst[1] = make_float4(0.f, 0.f, 0.f, 0.f);
        dst[2] = make_float4(0.f, 0.f, __int_as_float(center), 0.f);
    }
}

// One 32-output chunk of a dense layer: acc = B[p*32..] + W[:, p*32..+32]^T x
// x comes from LDS column xbuf[kk*64+lane]; W rows are float4 vector loads
// (uniform address across lanes -> broadcast; in-order vmcnt -> pipelinable).
template<int IN, int OUT>
__device__ __forceinline__ void layer_pass(const float* __restrict__ W,
                                           const float* __restrict__ Bb,
                                           const float* __restrict__ xbuf,
                                           int lane, int p, float acc[32])
{
    #pragma unroll
    for (int u = 0; u < 32; ++u) acc[u] = Bb[p * 32 + u];
    const float* __restrict__ Wc = W + p * 32;
    #pragma unroll 2
    for (int kk = 0; kk < IN; ++kk) {
        const float xv = xbuf[kk * 64 + lane];
        const float4* __restrict__ w = (const float4*)(Wc + (size_t)kk * OUT);
        #pragma unroll
        for (int q = 0; q < 8; ++q) {
            const float4 wv = w[q];
            acc[q * 4 + 0] = fmaf(xv, wv.x, acc[q * 4 + 0]);
            acc[q * 4 + 1] = fmaf(xv, wv.y, acc[q * 4 + 1]);
            acc[q * 4 + 2] = fmaf(xv, wv.z, acc[q * 4 + 2]);
            acc[q * 4 + 3] = fmaf(xv, wv.w, acc[q * 4 + 3]);
        }
    }
}

// ---------------- K2: MLP over compacted rows, 1 wave/block -----------------
__global__ __launch_bounds__(64)
void mlp_kernel(const float* __restrict__ rows, const int* __restrict__ ctr,
                const float* __restrict__ W0, const float* __restrict__ B0,
                const float* __restrict__ W1, const float* __restrict__ B1,
                const float* __restrict__ W2, const float* __restrict__ B2,
                const float* __restrict__ W3, const float* __restrict__ B3,
                const float* __restrict__ W4, const float* __restrict__ B4,
                const float* __restrict__ W5, const float* __restrict__ B5,
                const float* __restrict__ W6, const float* __restrict__ B6,
                float* __restrict__ out)
{
    __shared__ float bufA[128 * 64];   // 32 KB
    __shared__ float bufB[128 * 64];   // 32 KB
    const int lane = threadIdx.x;
    const int nrows = *ctr;            // multiple of 16

    for (int r0 = blockIdx.x * 64; r0 < nrows; r0 += K2_BLOCKS * 64) {
        const int r = r0 + lane;
        float sm = 0.f;
        int centr = -1;
        {
            float4 v0 = make_float4(0,0,0,0), v1 = v0, v2 = v0;
            if (r < nrows) {
                const float4* rec = (const float4*)(rows + (size_t)r * REC);
                v0 = rec[0]; v1 = rec[1]; v2 = rec[2];
                sm = v2.y;
                centr = __float_as_int(v2.z);
            }
            bufA[0*64+lane]=v0.x; bufA[1*64+lane]=v0.y; bufA[2*64+lane]=v0.z;
            bufA[3*64+lane]=v0.w; bufA[4*64+lane]=v1.x; bufA[5*64+lane]=v1.y;
            bufA[6*64+lane]=v1.z; bufA[7*64+lane]=v1.w; bufA[8*64+lane]=v2.x;
        }

        float res0[32], res1[32];
        float acc[32];

        // L0: 9 -> 64, A -> B ; xres kept in res*
        #pragma unroll 1
        for (int p = 0; p < 2; ++p) {
            layer_pass<9, 64>(W0, B0, bufA, lane, p, acc);
            float* rp = p ? res1 : res0;
            #pragma unroll
            for (int u = 0; u < 32; ++u) {
                const float h = ftanh(acc[u]);
                rp[u] = h;
                bufB[(p * 32 + u) * 64 + lane] = h;
            }
        }
        // L1: B -> A ; blk1 = h + xres -> res*, A
        #pragma unroll 1
        for (int p = 0; p < 2; ++p) {
            layer_pass<64, 64>(W1, B1, bufB, lane, p, acc);
            float* rp = p ? res1 : res0;
            #pragma unroll
            for (int u = 0; u < 32; ++u) {
                const float v = rp[u] + ftanh(acc[u]);
                rp[u] = v;
                bufA[(p * 32 + u) * 64 + lane] = v;
            }
        }
        // L2: A -> B
        #pragma unroll 1
        for (int p = 0; p < 2; ++p) {
            layer_pass<64, 64>(W2, B2, bufA, lane, p, acc);
            #pragma unroll
            for (int u = 0; u < 32; ++u)
                bufB[(p * 32 + u) * 64 + lane] = ftanh(acc[u]);
        }
        // L3: B -> A
        #pragma unroll 1
        for (int p = 0; p < 2; ++p) {
            layer_pass<64, 64>(W3, B3, bufB, lane, p, acc);
            #pragma unroll
            for (int u = 0; u < 32; ++u)
                bufA[(p * 32 + u) * 64 + lane] = ftanh(acc[u]);
        }
        // L4: A -> B ; blk2 = h + blk1
        #pragma unroll 1
        for (int p = 0; p < 2; ++p) {
            layer_pass<64, 64>(W4, B4, bufA, lane, p, acc);
            const float* rp = p ? res1 : res0;
            #pragma unroll
            for (int u = 0; u < 32; ++u)
                bufB[(p * 32 + u) * 64 + lane] = rp[u] + ftanh(acc[u]);
        }
        // L5: 64 -> 128, B -> A
        #pragma unroll 1
        for (int p = 0; p < 4; ++p) {
            layer_pass<64, 128>(W5, B5, bufB, lane, p, acc);
            #pragma unroll
            for (int u = 0; u < 32; ++u)
                bufA[(p * 32 + u) * 64 + lane] = ftanh(acc[u]);
        }
        // L6: 128 -> 256, A -> (reduce) -> atomics
        #pragma unroll 1
        for (int oc = 0; oc < 8; ++oc) {
            layer_pass<128, 256>(W6, B6, bufA, lane, oc, acc);
            #pragma unroll
            for (int u = 0; u < 32; ++u) {
                float v = ftanh(acc[u]) * sm;
                v += __shfl_xor(v, 1);
                v += __shfl_xor(v, 2);
                v += __shfl_xor(v, 4);
                v += __shfl_xor(v, 8);
                acc[u] = v;
            }
            if (((lane & 15) == 0) && centr >= 0) {
                float* __restrict__ op = out + (size_t)centr * 256 + oc * 32;
                #pragma unroll
                for (int u = 0; u < 32; ++u) atomicAdd(op + u, acc[u]);
            }
        }
    }
}

} // namespace

extern "C" void kernel_launch(void* const* d_in, const int* in_sizes, int n_in,
                              void* d_out, int out_size, void* d_ws, size_t ws_size,
                              hipStream_t stream) {
    (void)in_sizes; (void)n_in;

    const float* D  = (const float*)d_in[0];
    const float* Z  = (const float*)d_in[1];
    const float* W0 = (const float*)d_in[2];  const float* B0 = (const float*)d_in[3];
    const float* W1 = (const float*)d_in[4];  const float* B1 = (const float*)d_in[5];
    const float* W2 = (const float*)d_in[6];  const float* B2 = (const float*)d_in[7];
    const float* W3 = (const float*)d_in[8];  const float* B3 = (const float*)d_in[9];
    const float* W4 = (const float*)d_in[10]; const float* B4 = (const float*)d_in[11];
    const float* W5 = (const float*)d_in[12]; const float* B5 = (const float*)d_in[13];
    const float* W6 = (const float*)d_in[14]; const float* B6 = (const float*)d_in[15];
    float* out = (float*)d_out;

    int* ctr = (int*)d_ws;
    float* rowbuf = (float*)((char*)d_ws + 64);
    size_t avail = (ws_size > 64) ? (ws_size - 64) / (REC * sizeof(float)) : 0;
    int maxrows = (int)((avail < (size_t)MAXROWS_HARD) ? avail : (size_t)MAXROWS_HARD);

    hipMemsetAsync(d_ws, 0, 64, stream);
    hipMemsetAsync(d_out, 0, sizeof(float) * (size_t)out_size, stream);

    feat_kernel<<<1024, 64, 0, stream>>>(D, Z, rowbuf, ctr, maxrows);
    mlp_kernel<<<K2_BLOCKS, 64, 0, stream>>>(rowbuf, ctr,
                                             W0, B0, W1, B1, W2, B2, W3, B3,
                                             W4, B4, W5, B5, W6, B6, out);
}

// Round 6
// 412.898 us; speedup vs baseline: 4.0853x; 4.0853x over previous
//
#include <hip/hip_runtime.h>

namespace {

constexpr int T = 465;        // (N-1)(N-2)/2 triplets per center
constexpr int M = 31;         // "others" count
constexpr float FCUT = 3.5f;
constexpr float PI_OVER_CUT = 0.8975979010256552f; // pi/3.5
constexpr int REC = 12;       // floats per compacted row record
constexpr int K2_BLOCKS = 512;
constexpr int MAXROWS_HARD = 1024 * 480;

// LDS arena layout (float offsets). WB must be immediately followed by B so
// L6 can stage a [128][64] weight chunk into WB∪B (8192 floats) contiguously.
constexpr int OFF_WB = 0;         // 4096 floats (16 KB) weight stage
constexpr int OFF_B  = 4096;      // 4096 floats activations B
constexpr int OFF_A  = 8192;      // 4096 floats activations A
constexpr int OFF_C  = 12288;     // 4096 floats activations C
constexpr int OFF_F  = 16384;     // 9*64 input features
constexpr int OFF_SM = 16960;     // 64 smooth weights
constexpr int OFF_CT = 17024;     // 64 center ids (int)
constexpr int LDS_FLOATS = 17088; // 68352 bytes -> 2 blocks/CU

__device__ __forceinline__ float ftanh(float x) {
    x = fminf(fmaxf(x, -15.0f), 15.0f);
    const float e = __expf(2.0f * x);
    return (e - 1.0f) * __builtin_amdgcn_rcpf(e + 1.0f);
}

// ---------------- K1: compact active triplets into global row list ----------
__global__ __launch_bounds__(64, 1)
void feat_kernel(const float* __restrict__ D, const float* __restrict__ Z,
                 float* __restrict__ rows, int* __restrict__ ctr, int maxrows)
{
    const int lane = threadIdx.x;
    const int center = blockIdx.x;
    const int bi = center >> 5, i = center & 31;
    const float* __restrict__ Drow = D + bi * 1024;
    const float* __restrict__ Zrow = Z + bi * 32;
    const float z_i = Zrow[i];

    unsigned long long masks[8];
    int cnt = 0;
    #pragma unroll
    for (int rnd = 0; rnd < 8; ++rnd) {
        const int t = rnd * 64 + lane;
        bool act = false;
        if (t < T) {
            int a = 0, rem = t;
            while (rem >= M - 1 - a) { rem -= M - 1 - a; ++a; }
            const int b = a + 1 + rem;
            const int j = a + (a >= i);
            const int k = b + (b >= i);
            const float rij = Drow[i * 32 + j];
            const float rik = Drow[i * 32 + k];
            act = (rij < FCUT) && (rik < FCUT);
        }
        masks[rnd] = __ballot(act);
        cnt += (int)__popcll(masks[rnd]);
    }
    const int padded = (cnt + 15) & ~15;   // every 16-segment belongs to one center
    if (padded == 0) return;
    int base = 0;
    if (lane == 0) base = atomicAdd(ctr, padded);
    base = __shfl(base, 0);
    if (base + padded > maxrows) return;

    int pre = 0;
    #pragma unroll
    for (int rnd = 0; rnd < 8; ++rnd) {
        const unsigned long long mb = masks[rnd];
        const bool act = (mb >> lane) & 1ull;
        const int slot = base + pre + (int)__popcll(mb & ((1ull << lane) - 1ull));
        pre += (int)__popcll(mb);
        if (act) {
            const int t = rnd * 64 + lane;
            int a = 0, rem = t;
            while (rem >= M - 1 - a) { rem -= M - 1 - a; ++a; }
            const int b = a + 1 + rem;
            const int j = a + (a >= i);
            const int k = b + (b >= i);
            const float rij = Drow[i * 32 + j];
            const float rik = Drow[i * 32 + k];
            const float rjk = Drow[j * 32 + k];
            const float zj = Zrow[j], zk = Zrow[k];
            const float rij2 = rij * rij, rik2 = rik * rik, rjk2 = rjk * rjk;
            const float ci = (rij2 + rik2 - rjk2) / fmaxf(2.f * rij * rik, 1e-10f);
            const float cj = (rij2 + rjk2 - rik2) / fmaxf(2.f * rij * rjk, 1e-10f);
            const float ck = (rik2 + rjk2 - rij2) / fmaxf(2.f * rik * rjk, 1e-10f);
            const float g0 = rij + rik + rjk;
            const float g1 = rij * rik + rij * rjk + rik * rjk;
            const float g2 = rij * rik * rjk;
            const float rg = 1.0f / (sqrtf(g0 * g0 + g1 * g1 + g2 * g2) + 1e-7f);
            const float s0 = z_i + zj + zk;
            const float s1 = ci + cj + ck;
            const float s2 = z_i * (zj + zk) + zj * zk - ci * (cj + ck) - cj * ck;
            const float s3 = z_i * (cj + ck) + ci * (zj + zk) + zj * ck + cj * zk;
            const float s4 = z_i * (zj * zk - cj * ck) - ci * (zj * ck + cj * zk);
            const float s5 = z_i * (zj * ck + cj * zk) + ci * (zj * zk - cj * ck);
            const float rs = 1.0f / (sqrtf(s0*s0 + s1*s1 + s2*s2 + s3*s3 + s4*s4 + s5*s5) + 1e-7f);
            const float fij = 0.5f * cosf(PI_OVER_CUT * rij) + 0.5f;
            const float fik = 0.5f * cosf(PI_OVER_CUT * rik) + 0.5f;
            float4* dst = (float4*)(rows + (size_t)slot * REC);
            dst[0] = make_float4(g0 * rg, g1 * rg, g2 * rg, s0 * rs);
            dst[1] = make_float4(s1 * rs, s2 * rs, s3 * rs, s4 * rs);
            dst[2] = make_float4(s5 * rs, fij * fik, __int_as_float(center), 0.f);
        }
    }
    for (int p = cnt + lane; p < padded; p += 64) {
        float4* dst = (float4*)(rows + (size_t)(base + p) * REC);
        dst[0] = make_float4(0.f, 0.f, 0.f, 0.f);
        dst[1] = make_float4(0.f, 0.f, 0.f, 0.f);
        dst[2] = make_float4(0.f, 0.f, __int_as_float(center), 0.f);
    }
}

// Stage a [INF][64]-column chunk of weights (row-major, row stride OUT, column
// offset c0) into LDS. 256 threads, float4 each.
template<int INF>
__device__ __forceinline__ void stage_w(const float* __restrict__ W, int OUT, int c0,
                                        float* __restrict__ wb, int t)
{
    constexpr int TOT = INF * 64 / 4;   // float4 count
    #pragma unroll 1
    for (int idx = t; idx < TOT; idx += 256) {
        const int f = idx * 4;
        const int kk = f >> 6;
        const int c = f & 63;
        *(float4*)(wb + f) = *(const float4*)(W + (size_t)kk * OUT + c0 + c);
    }
}

// acc[0..16) += sum_kk x[kk] * WB[kk][wcol..wcol+16), x from [feat][row] LDS.
template<int INF>
__device__ __forceinline__ void accum(const float* __restrict__ wb,
                                      const float* __restrict__ xin,
                                      int lane, int wcol, float acc[16])
{
    #pragma unroll 4
    for (int kk = 0; kk < INF; ++kk) {
        const float x = xin[kk * 64 + lane];
        const float* wr = wb + kk * 64 + wcol;
        const float4 w0 = *(const float4*)(wr + 0);
        const float4 w1 = *(const float4*)(wr + 4);
        const float4 w2 = *(const float4*)(wr + 8);
        const float4 w3 = *(const float4*)(wr + 12);
        acc[ 0] = fmaf(x, w0.x, acc[ 0]);  acc[ 1] = fmaf(x, w0.y, acc[ 1]);
        acc[ 2] = fmaf(x, w0.z, acc[ 2]);  acc[ 3] = fmaf(x, w0.w, acc[ 3]);
        acc[ 4] = fmaf(x, w1.x, acc[ 4]);  acc[ 5] = fmaf(x, w1.y, acc[ 5]);
        acc[ 6] = fmaf(x, w1.z, acc[ 6]);  acc[ 7] = fmaf(x, w1.w, acc[ 7]);
        acc[ 8] = fmaf(x, w2.x, acc[ 8]);  acc[ 9] = fmaf(x, w2.y, acc[ 9]);
        acc[10] = fmaf(x, w2.z, acc[10]);  acc[11] = fmaf(x, w2.w, acc[11]);
        acc[12] = fmaf(x, w3.x, acc[12]);  acc[13] = fmaf(x, w3.y, acc[13]);
        acc[14] = fmaf(x, w3.z, acc[14]);  acc[15] = fmaf(x, w3.w, acc[15]);
    }
}

__device__ __forceinline__ void bias_init(const float* __restrict__ Bp, int off,
                                          float acc[16])
{
    const float4 b0 = *(const float4*)(Bp + off + 0);
    const float4 b1 = *(const float4*)(Bp + off + 4);
    const float4 b2 = *(const float4*)(Bp + off + 8);
    const float4 b3 = *(const float4*)(Bp + off + 12);
    acc[0]=b0.x; acc[1]=b0.y; acc[2]=b0.z; acc[3]=b0.w;
    acc[4]=b1.x; acc[5]=b1.y; acc[6]=b1.z; acc[7]=b1.w;
    acc[8]=b2.x; acc[9]=b2.y; acc[10]=b2.z; acc[11]=b2.w;
    acc[12]=b3.x; acc[13]=b3.y; acc[14]=b3.z; acc[15]=b3.w;
}

// ---------------- K2: MLP over compacted rows -------------------------------
// 256 threads (4 waves) per 64-row tile. Waves split the output dimension
// (16 outputs each). Weights staged per layer into LDS, read as wave-uniform
// ds_read_b128 broadcasts. Activations in shared [feat][row] LDS columns.
__global__ __launch_bounds__(256, 2)
void mlp_kernel(const float* __restrict__ rows, const int* __restrict__ ctr,
                const float* __restrict__ W0, const float* __restrict__ B0,
                const float* __restrict__ W1, const float* __restrict__ B1,
                const float* __restrict__ W2, const float* __restrict__ B2,
                const float* __restrict__ W3, const float* __restrict__ B3,
                const float* __restrict__ W4, const float* __restrict__ B4,
                const float* __restrict__ W5, const float* __restrict__ B5,
                const float* __restrict__ W6, const float* __restrict__ B6,
                float* __restrict__ out, int maxrows)
{
    __shared__ float lds[LDS_FLOATS];
    float* __restrict__ WB = lds + OFF_WB;
    float* __restrict__ Bb = lds + OFF_B;
    float* __restrict__ Ab = lds + OFF_A;
    float* __restrict__ Cb = lds + OFF_C;
    float* __restrict__ Fb = lds + OFF_F;
    float* __restrict__ SMb = lds + OFF_SM;
    int*   __restrict__ CTb = (int*)(lds + OFF_CT);

    const int t = threadIdx.x;
    const int lane = t & 63;
    const int wcol = (t >> 6) * 16;          // this wave's output base
    int nrows = *ctr;                        // multiple of 16
    if (nrows > maxrows) nrows = maxrows & ~15;

    for (int tile = blockIdx.x; tile * 64 < nrows; tile += K2_BLOCKS) {
        __syncthreads();   // previous tile fully consumed LDS
        if (t < 64) {
            const int r = tile * 64 + t;
            float4 v0 = make_float4(0,0,0,0), v1 = v0, v2 = v0;
            if (r < nrows) {
                const float4* rec = (const float4*)(rows + (size_t)r * REC);
                v0 = rec[0]; v1 = rec[1]; v2 = rec[2];
            } else {
                v2.z = __int_as_float(-1);   // phantom row: no atomics
            }
            Fb[0*64+t]=v0.x; Fb[1*64+t]=v0.y; Fb[2*64+t]=v0.z;
            Fb[3*64+t]=v0.w; Fb[4*64+t]=v1.x; Fb[5*64+t]=v1.y;
            Fb[6*64+t]=v1.z; Fb[7*64+t]=v1.w; Fb[8*64+t]=v2.x;
            SMb[t] = v2.y;
            CTb[t] = __float_as_int(v2.z);
        }
        stage_w<9>(W0, 64, 0, WB, t);
        __syncthreads();

        float acc[16];

        // L0: F -> A (x_res)
        bias_init(B0, wcol, acc);
        accum<9>(WB, Fb, lane, wcol, acc);
        #pragma unroll
        for (int q = 0; q < 16; ++q) Ab[(wcol + q) * 64 + lane] = ftanh(acc[q]);

        __syncthreads();
        stage_w<64>(W1, 64, 0, WB, t);
        __syncthreads();
        // L1: A -> B, blk1 = h + x_res
        bias_init(B1, wcol, acc);
        accum<64>(WB, Ab, lane, wcol, acc);
        #pragma unroll
        for (int q = 0; q < 16; ++q) {
            const int f = (wcol + q) * 64 + lane;
            Bb[f] = ftanh(acc[q]) + Ab[f];
        }

        __syncthreads();
        stage_w<64>(W2, 64, 0, WB, t);
        __syncthreads();
        // L2: B -> C
        bias_init(B2, wcol, acc);
        accum<64>(WB, Bb, lane, wcol, acc);
        #pragma unroll
        for (int q = 0; q < 16; ++q) Cb[(wcol + q) * 64 + lane] = ftanh(acc[q]);

        __syncthreads();
        stage_w<64>(W3, 64, 0, WB, t);
        __syncthreads();
        // L3: C -> A
        bias_init(B3, wcol, acc);
        accum<64>(WB, Cb, lane, wcol, acc);
        #pragma unroll
        for (int q = 0; q < 16; ++q) Ab[(wcol + q) * 64 + lane] = ftanh(acc[q]);

        __syncthreads();
        stage_w<64>(W4, 64, 0, WB, t);
        __syncthreads();
        // L4: A -> B (in-place residual: blk2 = h + blk1)
        bias_init(B4, wcol, acc);
        accum<64>(WB, Ab, lane, wcol, acc);
        #pragma unroll
        for (int q = 0; q < 16; ++q) {
            const int f = (wcol + q) * 64 + lane;
            Bb[f] = ftanh(acc[q]) + Bb[f];
        }

        // L5: B -> A (cols 0..64) then B -> C (cols 64..128)
        __syncthreads();
        stage_w<64>(W5, 128, 0, WB, t);
        __syncthreads();
        bias_init(B5, wcol, acc);
        accum<64>(WB, Bb, lane, wcol, acc);
        #pragma unroll
        for (int q = 0; q < 16; ++q) Ab[(wcol + q) * 64 + lane] = ftanh(acc[q]);

        __syncthreads();
        stage_w<64>(W5, 128, 64, WB, t);
        __syncthreads();
        bias_init(B5, 64 + wcol, acc);
        accum<64>(WB, Bb, lane, wcol, acc);
        #pragma unroll
        for (int q = 0; q < 16; ++q) Cb[(wcol + q) * 64 + lane] = ftanh(acc[q]);

        // L6: (A|C) -> out, 4 chunks of 64 cols; chunk staged into WB∪B (32 KB)
        const float sm = SMb[lane];
        const int ct = CTb[lane];
        #pragma unroll 1
        for (int c0 = 0; c0 < 256; c0 += 64) {
            __syncthreads();                   // B (blk2) dead after L5; reuse
            stage_w<128>(W6, 256, c0, lds, t); // fills lds[0..8192) = WB∪B
            __syncthreads();
            float a6[16];
            bias_init(B6, c0 + wcol, a6);
            accum<64>(lds, Ab, lane, wcol, a6);            // kk 0..64
            accum<64>(lds + 64 * 64, Cb, lane, wcol, a6);  // kk 64..128
            #pragma unroll
            for (int q = 0; q < 16; ++q) {
                float v = ftanh(a6[q]) * sm;
                v += __shfl_xor(v, 1);
                v += __shfl_xor(v, 2);
                v += __shfl_xor(v, 4);
                v += __shfl_xor(v, 8);
                if (((lane & 15) == 0) && ct >= 0)
                    atomicAdd(out + (size_t)ct * 256 + c0 + wcol + q, v);
            }
        }
    }
}

} // namespace

extern "C" void kernel_launch(void* const* d_in, const int* in_sizes, int n_in,
                              void* d_out, int out_size, void* d_ws, size_t ws_size,
                              hipStream_t stream) {
    (void)in_sizes; (void)n_in;

    const float* D  = (const float*)d_in[0];
    const float* Z  = (const float*)d_in[1];
    const float* W0 = (const float*)d_in[2];  const float* B0 = (const float*)d_in[3];
    const float* W1 = (const float*)d_in[4];  const float* B1 = (const float*)d_in[5];
    const float* W2 = (const float*)d_in[6];  const float* B2 = (const float*)d_in[7];
    const float* W3 = (const float*)d_in[8];  const float* B3 = (const float*)d_in[9];
    const float* W4 = (const float*)d_in[10]; const float* B4 = (const float*)d_in[11];
    const float* W5 = (const float*)d_in[12]; const float* B5 = (const float*)d_in[13];
    const float* W6 = (const float*)d_in[14]; const float* B6 = (const float*)d_in[15];
    float* out = (float*)d_out;

    int* ctr = (int*)d_ws;
    float* rowbuf = (float*)((char*)d_ws + 64);
    size_t avail = (ws_size > 64) ? (ws_size - 64) / (REC * sizeof(float)) : 0;
    int maxrows = (int)((avail < (size_t)MAXROWS_HARD) ? avail : (size_t)MAXROWS_HARD);

    hipMemsetAsync(d_ws, 0, 64, stream);
    hipMemsetAsync(d_out, 0, sizeof(float) * (size_t)out_size, stream);

    feat_kernel<<<1024, 64, 0, stream>>>(D, Z, rowbuf, ctr, maxrows);
    mlp_kernel<<<K2_BLOCKS, 256, 0, stream>>>(rowbuf, ctr,
                                              W0, B0, W1, B1, W2, B2, W3, B3,
                                              W4, B4, W5, B5, W6, B6, out, maxrows);
}